// Round 20
// baseline (401.507 us; speedup 1.0000x reference)
//
#include <hip/hip_runtime.h>
#include <math.h>

// Problem constants (reference: N=8192, DIM=512, TOPK=10, all fp32)
#define NROWS 8192
#define DIMK  512
#define TOPK  10
#define SCALE 0.044194173824159223f   // fp32(512**-0.5)

// Phase-1 embed GEMM tiling (fp32 VALU): 128x128 tile, 8x8 micro, dbuf, ETK16
#define ETM 128
#define ETN 128
#define ETK 16
#define NTHREADS 256

// Screen GEMM tiling (bf16 MFMA): BN 256, dbuf, aliased epilogue pool
#define BM 128
#define BN 256
#define BK 32
#define NS2 16                    // column strips (grid 64x16 = 1024 blocks)
#define SCOLS2 (NROWS / NS2)      // 512 cols per strip (2 tiles of 256)
#define NQ 256                    // 32-col groups per row (8192/32)
#define CAP 64                    // max candidates per row
#define TMARGIN 2.0f              // bf16-gemm noise (~0.65) + bf16-storage (~0.35) << 2.0

typedef __attribute__((ext_vector_type(8))) short bf16x8;   // 8 bf16 = 4 VGPRs
typedef __attribute__((ext_vector_type(4))) float f32x4;
typedef __attribute__((ext_vector_type(2))) float f32x2;
typedef __attribute__((ext_vector_type(4))) unsigned int u32x4;

__device__ __forceinline__ unsigned short f2bf(float f) {   // RNE fp32->bf16
  unsigned int u = __float_as_uint(f);
  u = (u + 0x7FFF + ((u >> 16) & 1)) >> 16;
  return (unsigned short)u;
}

// async global->LDS, 16B per lane; lds ptr must be wave-uniform base
__device__ __forceinline__ void gld16(const void* g, const void* lds) {
  __builtin_amdgcn_global_load_lds(
      (const __attribute__((address_space(1))) void*)g,
      (__attribute__((address_space(3))) void*)lds, 16, 0, 0);
}

// packed fp32 FMA: two INDEPENDENT exact IEEE fmas (v_pk_fma_f32). Each
// accumulator element's k-chain is unchanged -> bit-identical results.
__device__ __forceinline__ f32x2 pk_fma(f32x2 a, f32x2 b, f32x2 c) {
#if __has_builtin(__builtin_elementwise_fma)
  return __builtin_elementwise_fma(a, b, c);
#else
  f32x2 r; r[0] = fmaf(a[0], b[0], c[0]); r[1] = fmaf(a[1], b[1], c[1]);
  return r;
#endif
}

// 16-B streaming store (bypass L2): Sc is written once here and read once
// by the next kernel — caching it only evicts screen's Ehb/Etb working set.
__device__ __forceinline__ void nt_store16(void* p, uint4 v) {
#if __has_builtin(__builtin_nontemporal_store)
  u32x4 x; x[0] = v.x; x[1] = v.y; x[2] = v.z; x[3] = v.w;
  __builtin_nontemporal_store(x, (u32x4*)p);
#else
  *(uint4*)p = v;
#endif
}

// ---------------------------------------------------------------------------
// Phase 1 (byte-identical to r18): E = X @ W^T + b + bf16 copies. 128x128
// tile, 8x8 micro, packed FMA, dbuf, ETK=16. Per-element k-chain:
// sequential ascending fma + bias at end -> BIT-IDENTICAL Eh/Et vs r3-19.
// ---------------------------------------------------------------------------
__global__ __launch_bounds__(NTHREADS, 2)
void embed_gemm(const float* __restrict__ X,
                const float* __restrict__ Wh, const float* __restrict__ bh,
                const float* __restrict__ Wt, const float* __restrict__ bt,
                float* __restrict__ Eh, float* __restrict__ Et,
                unsigned short* __restrict__ Ehb, unsigned short* __restrict__ Etb) {
  __shared__ float As[2][ETK][ETM + 4];   // 2 x 8.4 KB, d-major
  __shared__ float Bs[2][ETK][ETN + 4];   // 2 x 8.4 KB

  const int tid = threadIdx.x;
  const int rowBase = blockIdx.x * ETM;
  const int colBase = blockIdx.y * ETN;          // 0..896 over [Wh|Wt]
  const float* W  = (colBase < DIMK) ? Wh : Wt;
  const float* bb = (colBase < DIMK) ? bh : bt;
  float* Out            = (colBase < DIMK) ? Eh : Et;
  unsigned short* Outb  = (colBase < DIMK) ? Ehb : Etb;
  const int colOff = colBase & (DIMK - 1);

  const int tx = tid & 15, ty = tid >> 4;
  f32x2 acc2[8][4];
#pragma unroll
  for (int r = 0; r < 8; ++r)
#pragma unroll
    for (int p = 0; p < 4; ++p) acc2[r][p] = (f32x2){0.f, 0.f};

  auto stage = [&](int buf, int kt) {
#pragma unroll
    for (int u = 0; u < 2; ++u) {      // A tile: 512 float4 (4 per 16-k row)
      const int idx = tid + u * NTHREADS;
      const int r = idx >> 2;          // 0..127
      const int dc = idx & 3;          // k-quad within 16
      const float4 av = *(const float4*)&X[(size_t)(rowBase + r) * DIMK + kt + dc * 4];
      As[buf][dc * 4 + 0][r] = av.x; As[buf][dc * 4 + 1][r] = av.y;
      As[buf][dc * 4 + 2][r] = av.z; As[buf][dc * 4 + 3][r] = av.w;
    }
#pragma unroll
    for (int u = 0; u < 2; ++u) {      // B tile: 512 float4
      const int idx = tid + u * NTHREADS;
      const int r = idx >> 2;
      const int dc = idx & 3;
      const float4 bv = *(const float4*)&W[(size_t)(colOff + r) * DIMK + kt + dc * 4];
      Bs[buf][dc * 4 + 0][r] = bv.x; Bs[buf][dc * 4 + 1][r] = bv.y;
      Bs[buf][dc * 4 + 2][r] = bv.z; Bs[buf][dc * 4 + 3][r] = bv.w;
    }
  };
  auto compute = [&](int buf) {
#pragma unroll 4
    for (int k = 0; k < ETK; ++k) {
      const float4 a0 = *(const float4*)&As[buf][k][ty * 4];
      const float4 a1 = *(const float4*)&As[buf][k][64 + ty * 4];
      const float4 b0 = *(const float4*)&Bs[buf][k][tx * 4];
      const float4 b1 = *(const float4*)&Bs[buf][k][64 + tx * 4];
      const float ar[8] = {a0.x, a0.y, a0.z, a0.w, a1.x, a1.y, a1.z, a1.w};
      const f32x2 bp[4] = {(f32x2){b0.x, b0.y}, (f32x2){b0.z, b0.w},
                           (f32x2){b1.x, b1.y}, (f32x2){b1.z, b1.w}};
#pragma unroll
      for (int r = 0; r < 8; ++r) {
        const f32x2 ar2 = (f32x2){ar[r], ar[r]};
#pragma unroll
        for (int p = 0; p < 4; ++p)
          acc2[r][p] = pk_fma(ar2, bp[p], acc2[r][p]);
      }
    }
  };

  stage(0, 0);
  __syncthreads();
#pragma unroll 1
  for (int ki = 0; ki < DIMK / ETK; ki += 2) {
    if (ki + 1 < DIMK / ETK) stage(1, (ki + 1) * ETK);
    compute(0);                  // k ascending -> chain bit-identical
    __syncthreads();
    if (ki + 2 < DIMK / ETK) stage(0, (ki + 2) * ETK);
    compute(1);
    __syncthreads();
  }

  float br[8];
  {
    const float4 bv0 = *(const float4*)&bb[colOff + tx * 4];
    const float4 bv1 = *(const float4*)&bb[colOff + 64 + tx * 4];
    br[0] = bv0.x; br[1] = bv0.y; br[2] = bv0.z; br[3] = bv0.w;
    br[4] = bv1.x; br[5] = bv1.y; br[6] = bv1.z; br[7] = bv1.w;
  }
#pragma unroll
  for (int r = 0; r < 8; ++r) {
    const int row = rowBase + ((r < 4) ? (ty * 4 + r) : (64 + ty * 4 + r - 4));
    float4 o0, o1;
    o0.x = acc2[r][0][0] + br[0]; o0.y = acc2[r][0][1] + br[1];
    o0.z = acc2[r][1][0] + br[2]; o0.w = acc2[r][1][1] + br[3];
    o1.x = acc2[r][2][0] + br[4]; o1.y = acc2[r][2][1] + br[5];
    o1.z = acc2[r][3][0] + br[6]; o1.w = acc2[r][3][1] + br[7];
    const size_t off0 = (size_t)row * DIMK + colOff + tx * 4;
    const size_t off1 = off0 + 64;
    *(float4*)&Out[off0] = o0;
    *(float4*)&Out[off1] = o1;
    ushort4 q0, q1;
    q0.x = f2bf(o0.x); q0.y = f2bf(o0.y); q0.z = f2bf(o0.z); q0.w = f2bf(o0.w);
    q1.x = f2bf(o1.x); q1.y = f2bf(o1.y); q1.z = f2bf(o1.z); q1.w = f2bf(o1.w);
    *(ushort4*)&Outb[off0] = q0;
    *(ushort4*)&Outb[off1] = q1;
  }
}

// ---------------------------------------------------------------------------
// Screen (r16-r19 structure; ONE change: Sc stores are non-temporal).
// BN=256, dbuf, aliased 48-KB pool, (256,2), 128 VGPR no spill.
// acc BIT-IDENTICAL chain; same bits stored -> output unchanged.
// ---------------------------------------------------------------------------
__global__ __launch_bounds__(256, 2)
void screen_store(const unsigned short* __restrict__ Ehb,
                  const unsigned short* __restrict__ Etb,
                  float* __restrict__ tmax, unsigned short* __restrict__ Sc) {
  __shared__ unsigned short pool[2 * BM * BK + 2 * BN * BK];   // 49152 B
  unsigned short* const AsP[2] = {pool, pool + BM * BK};
  unsigned short* const BsP[2] = {pool + 2 * BM * BK, pool + 2 * BM * BK + BN * BK};
  unsigned short* const Csb = pool;   // epilogue alias

  const int tid = threadIdx.x;
  const int rowBase = blockIdx.x * BM;
  const int strip = blockIdx.y;
  const int w = tid >> 6, lane = tid & 63;
  const int q = lane >> 4, l15 = lane & 15;
  const int wr = (w & 1) * 64, wc = (w >> 1) * 128;
  const int rr = tid >> 1, hq = tid & 1;   // epilogue: row / 32-col chunk

  const int wb0 = __builtin_amdgcn_readfirstlane(tid & ~63);
  const int ar0 = tid >> 2,         ac0 = (tid & 3) * 8;
  const int ar1 = (tid + 256) >> 2, ac1 = ((tid + 256) & 3) * 8;

  for (int ct = 0; ct < SCOLS2; ct += BN) {
    const int colBase = strip * SCOLS2 + ct;
    f32x4 acc[4][8];
#pragma unroll
    for (int i = 0; i < 4; ++i)
#pragma unroll
      for (int j = 0; j < 8; ++j) acc[i][j] = (f32x4){0.f, 0.f, 0.f, 0.f};

    auto stage = [&](int buf, int kt) {
      gld16(Ehb + (size_t)(rowBase + ar0) * DIMK + kt + ac0, AsP[buf] + wb0 * 8);
      gld16(Ehb + (size_t)(rowBase + ar1) * DIMK + kt + ac1, AsP[buf] + (wb0 + 256) * 8);
#pragma unroll
      for (int u = 0; u < 4; ++u) {
        const int c = tid + u * 256;
        gld16(Etb + (size_t)(colBase + (c >> 2)) * DIMK + kt + (c & 3) * 8,
              BsP[buf] + (wb0 + u * 256) * 8);
      }
    };
    auto compute = [&](int buf) {
      bf16x8 af[4], bf[8];
#pragma unroll
      for (int i = 0; i < 4; ++i)
        af[i] = *(const bf16x8*)&AsP[buf][(wr + i * 16 + l15) * BK + q * 8];
#pragma unroll
      for (int j = 0; j < 8; ++j)
        bf[j] = *(const bf16x8*)&BsP[buf][(wc + j * 16 + l15) * BK + q * 8];
#pragma unroll
      for (int i = 0; i < 4; ++i)
#pragma unroll
        for (int j = 0; j < 8; ++j)
          acc[i][j] = __builtin_amdgcn_mfma_f32_16x16x32_bf16(af[i], bf[j], acc[i][j], 0, 0, 0);
    };

    stage(0, 0);
    __syncthreads();
#pragma unroll 1
    for (int ki = 0; ki < DIMK / BK; ki += 2) {
      if (ki + 1 < DIMK / BK) stage(1, (ki + 1) * BK);
      compute(0);
      __syncthreads();
      if (ki + 2 < DIMK / BK) stage(0, (ki + 2) * BK);
      compute(1);
      __syncthreads();
    }
    // K-loop done (final barrier passed): staging pool dead -> Csb valid.

#pragma unroll
    for (int qtr = 0; qtr < 4; ++qtr) {
      const int jbase = (qtr & 1) * 4;
      if ((w >> 1) == (qtr >> 1)) {
#pragma unroll
        for (int i = 0; i < 4; ++i)
#pragma unroll
          for (int jj = 0; jj < 4; ++jj)
#pragma unroll
            for (int rg = 0; rg < 4; ++rg)
              Csb[(wr + i * 16 + q * 4 + rg) * 72 + jj * 16 + l15] =
                  f2bf(acc[i][jbase + jj][rg]);
      }
      __syncthreads();
      float m = -INFINITY;
      uint4 buf4[4];
#pragma unroll
      for (int k = 0; k < 4; ++k) {
        buf4[k] = *(const uint4*)&Csb[rr * 72 + hq * 32 + k * 8];
        const unsigned int uu[4] = {buf4[k].x, buf4[k].y, buf4[k].z, buf4[k].w};
#pragma unroll
        for (int e = 0; e < 4; ++e) {
          m = fmaxf(m, __uint_as_float(uu[e] << 16));
          m = fmaxf(m, __uint_as_float(uu[e] & 0xFFFF0000u));
        }
      }
      const int gbase = (colBase + qtr * 64) >> 5;   // global 32-col group
      tmax[(size_t)(rowBase + rr) * NQ + gbase + hq] = m;
      unsigned short* dst = &Sc[(size_t)(rowBase + rr) * NROWS + colBase + qtr * 64 + hq * 32];
#pragma unroll
      for (int k = 0; k < 4; ++k) nt_store16(dst + k * 8, buf4[k]);
      __syncthreads();   // readback done before next dump / next ct staging
    }
  }
}

// ---------------------------------------------------------------------------
// Merged tail (byte-identical to r17/r18, best measured): block-per-row
// chunk-skip collect + wave-0 rescore. Candidate SET identical; selection
// value+min-col deterministic; chain BIT-IDENTICAL to r3-19.
// ---------------------------------------------------------------------------
__global__ __launch_bounds__(256)
void collect_rescore(const unsigned short* __restrict__ Sc,
                     const float* __restrict__ tmax,
                     const float* __restrict__ Eh, const float* __restrict__ Et,
                     float* __restrict__ out) {
  __shared__ float tm[NQ];     // 1 KB: the row's 256 group maxes
  __shared__ float tts;
  __shared__ int lcnt;
  __shared__ int lcand[CAP];
  const int tid = threadIdx.x;
  const int lane = tid & 63;
  const int wid = tid >> 6;
  const int r = blockIdx.x;

  if (tid == 0) lcnt = 0;
  tm[tid] = tmax[(size_t)r * NQ + tid];   // coalesced 1 KB row load
  __syncthreads();

  // --- threshold (wave 0): identical knockout semantics to r13-19 ---
  if (wid == 0) {
    float a0 = tm[lane * 4 + 0], a1 = tm[lane * 4 + 1];
    float a2 = tm[lane * 4 + 2], a3 = tm[lane * 4 + 3];
    float g = -INFINITY;
#pragma unroll 1
    for (int j = 0; j < TOPK; ++j) {
      const float lm = fmaxf(fmaxf(a0, a1), fmaxf(a2, a3));
      g = lm;
#pragma unroll
      for (int off = 32; off > 0; off >>= 1) g = fmaxf(g, __shfl_xor(g, off, 64));
      const unsigned long long ball = __ballot(lm == g);
      const int src = __ffsll((long long)ball) - 1;
      if (lane == src) {
        if      (a0 == g) a0 = -INFINITY;
        else if (a1 == g) a1 = -INFINITY;
        else if (a2 == g) a2 = -INFINITY;
        else              a3 = -INFINITY;
      }
    }
    if (lane == 0) tts = g - TMARGIN;
  }
  __syncthreads();
  const float tt = tts;

  // --- chunk-skip scan: thread t handles 32-col group t ---
  if (tm[tid] >= tt) {
    const unsigned short* chunk = Sc + (size_t)r * NROWS + tid * 32;
#pragma unroll
    for (int k = 0; k < 4; ++k) {
      const uint4 u = *(const uint4*)&chunk[k * 8];
      const unsigned int uu[4] = {u.x, u.y, u.z, u.w};
#pragma unroll
      for (int e = 0; e < 4; ++e) {
        const float lo = __uint_as_float(uu[e] << 16);
        const float hi = __uint_as_float(uu[e] & 0xFFFF0000u);
        const int c0 = tid * 32 + k * 8 + 2 * e;
        if (lo >= tt) {
          const int p = atomicAdd(&lcnt, 1);
          if (p < CAP) lcand[p] = c0;
        }
        if (hi >= tt) {
          const int p = atomicAdd(&lcnt, 1);
          if (p < CAP) lcand[p] = c0 + 1;
        }
      }
    }
  }
  __syncthreads();   // candidate list complete
  if (wid != 0) return;

  // --- rescore on wave 0: chain BIT-IDENTICAL to rounds 3-19 ---
  const int n = min(lcnt, CAP);
  const bool active = lane < n;
  const int col = active ? lcand[lane] : 0;

  const float* a = Eh + (size_t)r * DIMK;
  const float* b = Et + (size_t)col * DIMK;
  float p = 0.f;
#pragma unroll 4
  for (int k = 0; k < DIMK; k += 4) {
    const float4 av = *(const float4*)&a[k];
    const float4 bv = *(const float4*)&b[k];
    p = fmaf(av.x, bv.x, p);
    p = fmaf(av.y, bv.y, p);
    p = fmaf(av.z, bv.z, p);
    p = fmaf(av.w, bv.w, p);
  }
  float v = active ? p * SCALE : -INFINITY;
  const int vc = active ? col : 0x7FFFFFFF;

  // 10 rounds of wave-max (tie -> min col); lane j keeps round-j winner.
  float myv = -INFINITY; int myc = 0; float m = 0.f;
  float vv = v; int cc2 = vc;
#pragma unroll 1
  for (int j = 0; j < TOPK; ++j) {
    float bvv = vv; int bcc = cc2;
#pragma unroll
    for (int off = 32; off > 0; off >>= 1) {
      const float ov = __shfl_xor(bvv, off, 64);
      const int oc = __shfl_xor(bcc, off, 64);
      if (ov > bvv || (ov == bvv && oc < bcc)) { bvv = ov; bcc = oc; }
    }
    if (j == 0) m = bvv;
    if (lane == j) { myv = bvv; myc = bcc; }
    if (vv == bvv && cc2 == bcc) vv = -INFINITY;   // knock out (cols unique)
  }

  // softmax: gather the 10 values, sum sequentially (rank order, as before).
  float sum = 0.f;
#pragma unroll
  for (int j = 0; j < TOPK; ++j) sum += expf(__shfl(myv, j, 64) - m);
  const float inv = 1.0f / sum;

  if (lane < TOPK) {
    const size_t ro = (size_t)r * TOPK + lane;
    out[ro] = (float)r;                                   // src
    out[(size_t)NROWS * TOPK + ro] = (float)myc;          // dst
    out[2 * (size_t)NROWS * TOPK + ro] = expf(myv - m) * inv;  // weight
  }
}

// ---------------------------------------------------------------------------
extern "C" void kernel_launch(void* const* d_in, const int* in_sizes, int n_in,
                              void* d_out, int out_size, void* d_ws, size_t ws_size,
                              hipStream_t stream) {
  const float* X  = (const float*)d_in[0];
  const float* Wh = (const float*)d_in[1];
  const float* bh = (const float*)d_in[2];
  const float* Wt = (const float*)d_in[3];
  const float* bt = (const float*)d_in[4];
  float* out = (float*)d_out;

  char* ws = (char*)d_ws;
  const size_t embB  = (size_t)NROWS * DIMK * sizeof(float);          // 16 MB
  const size_t embBH = (size_t)NROWS * DIMK * sizeof(unsigned short); //  8 MB
  const size_t tmaxB = (size_t)NROWS * NQ * sizeof(float);            //  8 MB
  float* Eh   = (float*)ws;
  float* Et   = (float*)(ws + embB);
  unsigned short* Ehb = (unsigned short*)(ws + 2 * embB);
  unsigned short* Etb = (unsigned short*)(ws + 2 * embB + embBH);
  float* tmax = (float*)(ws + 2 * embB + 2 * embBH);
  unsigned short* Sc = (unsigned short*)(ws + 2 * embB + 2 * embBH + tmaxB);
  // total ws use ~176 MB

  dim3 blk(NTHREADS);
  dim3 g1(NROWS / ETM, (2 * DIMK) / ETN);      // 64 x 8
  embed_gemm<<<g1, blk, 0, stream>>>(X, Wh, bh, Wt, bt, Eh, Et, Ehb, Etb);

  dim3 g2(NROWS / BM, NS2);                    // 64 x 16 (1024 blocks)
  screen_store<<<g2, blk, 0, stream>>>(Ehb, Etb, tmax, Sc);

  collect_rescore<<<NROWS, blk, 0, stream>>>(Sc, tmax, Eh, Et, out);
}

// Round 21
// 360.297 us; speedup vs baseline: 1.1144x; 1.1144x over previous
//
#include <hip/hip_runtime.h>
#include <math.h>

// Problem constants (reference: N=8192, DIM=512, TOPK=10, all fp32)
#define NROWS 8192
#define DIMK  512
#define TOPK  10
#define SCALE 0.044194173824159223f   // fp32(512**-0.5)

// Phase-1 embed GEMM tiling (fp32 VALU): 128x128 tile, 8x8 micro, dbuf, ETK16
#define ETM 128
#define ETN 128
#define ETK 16
#define NTHREADS 256

// Screen GEMM tiling (bf16 MFMA): BN 256, dbuf, aliased epilogue pool
#define BM 128
#define BN 256
#define BK 32
#define NS2 16                    // column strips (grid 64x16 = 1024 blocks)
#define SCOLS2 (NROWS / NS2)      // 512 cols per strip (2 tiles of 256)
#define NQ 256                    // 32-col groups per row (8192/32)
#define CAP 64                    // max candidates per row
#define TMARGIN 2.0f              // bf16-gemm noise (~0.65) + bf16-storage (~0.35) << 2.0

typedef __attribute__((ext_vector_type(8))) short bf16x8;   // 8 bf16 = 4 VGPRs
typedef __attribute__((ext_vector_type(4))) float f32x4;
typedef __attribute__((ext_vector_type(2))) float f32x2;

__device__ __forceinline__ unsigned short f2bf(float f) {   // RNE fp32->bf16
  unsigned int u = __float_as_uint(f);
  u = (u + 0x7FFF + ((u >> 16) & 1)) >> 16;
  return (unsigned short)u;
}

// async global->LDS, 16B per lane; lds ptr must be wave-uniform base
__device__ __forceinline__ void gld16(const void* g, const void* lds) {
  __builtin_amdgcn_global_load_lds(
      (const __attribute__((address_space(1))) void*)g,
      (__attribute__((address_space(3))) void*)lds, 16, 0, 0);
}

// packed fp32 FMA: two INDEPENDENT exact IEEE fmas (v_pk_fma_f32). Each
// accumulator element's k-chain is unchanged -> bit-identical results.
__device__ __forceinline__ f32x2 pk_fma(f32x2 a, f32x2 b, f32x2 c) {
#if __has_builtin(__builtin_elementwise_fma)
  return __builtin_elementwise_fma(a, b, c);
#else
  f32x2 r; r[0] = fmaf(a[0], b[0], c[0]); r[1] = fmaf(a[1], b[1], c[1]);
  return r;
#endif
}

// ---------------------------------------------------------------------------
// Phase 1 (r18, best measured): E = X @ W^T + b + bf16 copies. 128x128
// tile, 8x8 micro, packed FMA, dbuf, ETK=16. Per-element k-chain:
// sequential ascending fma + bias at end -> BIT-IDENTICAL Eh/Et vs r3-20.
// ---------------------------------------------------------------------------
__global__ __launch_bounds__(NTHREADS, 2)
void embed_gemm(const float* __restrict__ X,
                const float* __restrict__ Wh, const float* __restrict__ bh,
                const float* __restrict__ Wt, const float* __restrict__ bt,
                float* __restrict__ Eh, float* __restrict__ Et,
                unsigned short* __restrict__ Ehb, unsigned short* __restrict__ Etb) {
  __shared__ float As[2][ETK][ETM + 4];   // 2 x 8.4 KB, d-major
  __shared__ float Bs[2][ETK][ETN + 4];   // 2 x 8.4 KB

  const int tid = threadIdx.x;
  const int rowBase = blockIdx.x * ETM;
  const int colBase = blockIdx.y * ETN;          // 0..896 over [Wh|Wt]
  const float* W  = (colBase < DIMK) ? Wh : Wt;
  const float* bb = (colBase < DIMK) ? bh : bt;
  float* Out            = (colBase < DIMK) ? Eh : Et;
  unsigned short* Outb  = (colBase < DIMK) ? Ehb : Etb;
  const int colOff = colBase & (DIMK - 1);

  const int tx = tid & 15, ty = tid >> 4;
  f32x2 acc2[8][4];
#pragma unroll
  for (int r = 0; r < 8; ++r)
#pragma unroll
    for (int p = 0; p < 4; ++p) acc2[r][p] = (f32x2){0.f, 0.f};

  auto stage = [&](int buf, int kt) {
#pragma unroll
    for (int u = 0; u < 2; ++u) {      // A tile: 512 float4 (4 per 16-k row)
      const int idx = tid + u * NTHREADS;
      const int r = idx >> 2;          // 0..127
      const int dc = idx & 3;          // k-quad within 16
      const float4 av = *(const float4*)&X[(size_t)(rowBase + r) * DIMK + kt + dc * 4];
      As[buf][dc * 4 + 0][r] = av.x; As[buf][dc * 4 + 1][r] = av.y;
      As[buf][dc * 4 + 2][r] = av.z; As[buf][dc * 4 + 3][r] = av.w;
    }
#pragma unroll
    for (int u = 0; u < 2; ++u) {      // B tile: 512 float4
      const int idx = tid + u * NTHREADS;
      const int r = idx >> 2;
      const int dc = idx & 3;
      const float4 bv = *(const float4*)&W[(size_t)(colOff + r) * DIMK + kt + dc * 4];
      Bs[buf][dc * 4 + 0][r] = bv.x; Bs[buf][dc * 4 + 1][r] = bv.y;
      Bs[buf][dc * 4 + 2][r] = bv.z; Bs[buf][dc * 4 + 3][r] = bv.w;
    }
  };
  auto compute = [&](int buf) {
#pragma unroll 4
    for (int k = 0; k < ETK; ++k) {
      const float4 a0 = *(const float4*)&As[buf][k][ty * 4];
      const float4 a1 = *(const float4*)&As[buf][k][64 + ty * 4];
      const float4 b0 = *(const float4*)&Bs[buf][k][tx * 4];
      const float4 b1 = *(const float4*)&Bs[buf][k][64 + tx * 4];
      const float ar[8] = {a0.x, a0.y, a0.z, a0.w, a1.x, a1.y, a1.z, a1.w};
      const f32x2 bp[4] = {(f32x2){b0.x, b0.y}, (f32x2){b0.z, b0.w},
                           (f32x2){b1.x, b1.y}, (f32x2){b1.z, b1.w}};
#pragma unroll
      for (int r = 0; r < 8; ++r) {
        const f32x2 ar2 = (f32x2){ar[r], ar[r]};
#pragma unroll
        for (int p = 0; p < 4; ++p)
          acc2[r][p] = pk_fma(ar2, bp[p], acc2[r][p]);
      }
    }
  };

  stage(0, 0);
  __syncthreads();
#pragma unroll 1
  for (int ki = 0; ki < DIMK / ETK; ki += 2) {
    if (ki + 1 < DIMK / ETK) stage(1, (ki + 1) * ETK);
    compute(0);                  // k ascending -> chain bit-identical
    __syncthreads();
    if (ki + 2 < DIMK / ETK) stage(0, (ki + 2) * ETK);
    compute(1);
    __syncthreads();
  }

  float br[8];
  {
    const float4 bv0 = *(const float4*)&bb[colOff + tx * 4];
    const float4 bv1 = *(const float4*)&bb[colOff + 64 + tx * 4];
    br[0] = bv0.x; br[1] = bv0.y; br[2] = bv0.z; br[3] = bv0.w;
    br[4] = bv1.x; br[5] = bv1.y; br[6] = bv1.z; br[7] = bv1.w;
  }
#pragma unroll
  for (int r = 0; r < 8; ++r) {
    const int row = rowBase + ((r < 4) ? (ty * 4 + r) : (64 + ty * 4 + r - 4));
    float4 o0, o1;
    o0.x = acc2[r][0][0] + br[0]; o0.y = acc2[r][0][1] + br[1];
    o0.z = acc2[r][1][0] + br[2]; o0.w = acc2[r][1][1] + br[3];
    o1.x = acc2[r][2][0] + br[4]; o1.y = acc2[r][2][1] + br[5];
    o1.z = acc2[r][3][0] + br[6]; o1.w = acc2[r][3][1] + br[7];
    const size_t off0 = (size_t)row * DIMK + colOff + tx * 4;
    const size_t off1 = off0 + 64;
    *(float4*)&Out[off0] = o0;
    *(float4*)&Out[off1] = o1;
    ushort4 q0, q1;
    q0.x = f2bf(o0.x); q0.y = f2bf(o0.y); q0.z = f2bf(o0.z); q0.w = f2bf(o0.w);
    q1.x = f2bf(o1.x); q1.y = f2bf(o1.y); q1.z = f2bf(o1.z); q1.w = f2bf(o1.w);
    *(ushort4*)&Outb[off0] = q0;
    *(ushort4*)&Outb[off1] = q1;
  }
}

// ---------------------------------------------------------------------------
// Screen (r16/r18, best measured 121-133 us): BN=256, dbuf, aliased 48-KB
// pool, (256,2), 128 VGPR no spill, REGULAR uint4 Sc stores (r20's NT
// stores regressed: WRITE 212->262 MB, dur +44 us). acc BIT-IDENTICAL.
// ---------------------------------------------------------------------------
__global__ __launch_bounds__(256, 2)
void screen_store(const unsigned short* __restrict__ Ehb,
                  const unsigned short* __restrict__ Etb,
                  float* __restrict__ tmax, unsigned short* __restrict__ Sc) {
  __shared__ unsigned short pool[2 * BM * BK + 2 * BN * BK];   // 49152 B
  unsigned short* const AsP[2] = {pool, pool + BM * BK};
  unsigned short* const BsP[2] = {pool + 2 * BM * BK, pool + 2 * BM * BK + BN * BK};
  unsigned short* const Csb = pool;   // epilogue alias

  const int tid = threadIdx.x;
  const int rowBase = blockIdx.x * BM;
  const int strip = blockIdx.y;
  const int w = tid >> 6, lane = tid & 63;
  const int q = lane >> 4, l15 = lane & 15;
  const int wr = (w & 1) * 64, wc = (w >> 1) * 128;
  const int rr = tid >> 1, hq = tid & 1;   // epilogue: row / 32-col chunk

  const int wb0 = __builtin_amdgcn_readfirstlane(tid & ~63);
  const int ar0 = tid >> 2,         ac0 = (tid & 3) * 8;
  const int ar1 = (tid + 256) >> 2, ac1 = ((tid + 256) & 3) * 8;

  for (int ct = 0; ct < SCOLS2; ct += BN) {
    const int colBase = strip * SCOLS2 + ct;
    f32x4 acc[4][8];
#pragma unroll
    for (int i = 0; i < 4; ++i)
#pragma unroll
      for (int j = 0; j < 8; ++j) acc[i][j] = (f32x4){0.f, 0.f, 0.f, 0.f};

    auto stage = [&](int buf, int kt) {
      gld16(Ehb + (size_t)(rowBase + ar0) * DIMK + kt + ac0, AsP[buf] + wb0 * 8);
      gld16(Ehb + (size_t)(rowBase + ar1) * DIMK + kt + ac1, AsP[buf] + (wb0 + 256) * 8);
#pragma unroll
      for (int u = 0; u < 4; ++u) {
        const int c = tid + u * 256;
        gld16(Etb + (size_t)(colBase + (c >> 2)) * DIMK + kt + (c & 3) * 8,
              BsP[buf] + (wb0 + u * 256) * 8);
      }
    };
    auto compute = [&](int buf) {
      bf16x8 af[4], bf[8];
#pragma unroll
      for (int i = 0; i < 4; ++i)
        af[i] = *(const bf16x8*)&AsP[buf][(wr + i * 16 + l15) * BK + q * 8];
#pragma unroll
      for (int j = 0; j < 8; ++j)
        bf[j] = *(const bf16x8*)&BsP[buf][(wc + j * 16 + l15) * BK + q * 8];
#pragma unroll
      for (int i = 0; i < 4; ++i)
#pragma unroll
        for (int j = 0; j < 8; ++j)
          acc[i][j] = __builtin_amdgcn_mfma_f32_16x16x32_bf16(af[i], bf[j], acc[i][j], 0, 0, 0);
    };

    stage(0, 0);
    __syncthreads();
#pragma unroll 1
    for (int ki = 0; ki < DIMK / BK; ki += 2) {
      if (ki + 1 < DIMK / BK) stage(1, (ki + 1) * BK);
      compute(0);
      __syncthreads();
      if (ki + 2 < DIMK / BK) stage(0, (ki + 2) * BK);
      compute(1);
      __syncthreads();
    }
    // K-loop done (final barrier passed): staging pool dead -> Csb valid.

#pragma unroll
    for (int qtr = 0; qtr < 4; ++qtr) {
      const int jbase = (qtr & 1) * 4;
      if ((w >> 1) == (qtr >> 1)) {
#pragma unroll
        for (int i = 0; i < 4; ++i)
#pragma unroll
          for (int jj = 0; jj < 4; ++jj)
#pragma unroll
            for (int rg = 0; rg < 4; ++rg)
              Csb[(wr + i * 16 + q * 4 + rg) * 72 + jj * 16 + l15] =
                  f2bf(acc[i][jbase + jj][rg]);
      }
      __syncthreads();
      float m = -INFINITY;
      uint4 buf4[4];
#pragma unroll
      for (int k = 0; k < 4; ++k) {
        buf4[k] = *(const uint4*)&Csb[rr * 72 + hq * 32 + k * 8];
        const unsigned int uu[4] = {buf4[k].x, buf4[k].y, buf4[k].z, buf4[k].w};
#pragma unroll
        for (int e = 0; e < 4; ++e) {
          m = fmaxf(m, __uint_as_float(uu[e] << 16));
          m = fmaxf(m, __uint_as_float(uu[e] & 0xFFFF0000u));
        }
      }
      const int gbase = (colBase + qtr * 64) >> 5;   // global 32-col group
      tmax[(size_t)(rowBase + rr) * NQ + gbase + hq] = m;
      uint4* dst = (uint4*)&Sc[(size_t)(rowBase + rr) * NROWS + colBase + qtr * 64 + hq * 32];
#pragma unroll
      for (int k = 0; k < 4; ++k) dst[k] = buf4[k];
      __syncthreads();   // readback done before next dump / next ct staging
    }
  }
}

// ---------------------------------------------------------------------------
// Merged tail (r17/r18, best measured): block-per-row chunk-skip collect +
// wave-0 rescore. Candidate SET identical (chunk qualifies iff its stored
// max >= tt); selection value+min-col deterministic; chain BIT-IDENTICAL.
// ---------------------------------------------------------------------------
__global__ __launch_bounds__(256)
void collect_rescore(const unsigned short* __restrict__ Sc,
                     const float* __restrict__ tmax,
                     const float* __restrict__ Eh, const float* __restrict__ Et,
                     float* __restrict__ out) {
  __shared__ float tm[NQ];     // 1 KB: the row's 256 group maxes
  __shared__ float tts;
  __shared__ int lcnt;
  __shared__ int lcand[CAP];
  const int tid = threadIdx.x;
  const int lane = tid & 63;
  const int wid = tid >> 6;
  const int r = blockIdx.x;

  if (tid == 0) lcnt = 0;
  tm[tid] = tmax[(size_t)r * NQ + tid];   // coalesced 1 KB row load
  __syncthreads();

  // --- threshold (wave 0): identical knockout semantics to r13-20 ---
  if (wid == 0) {
    float a0 = tm[lane * 4 + 0], a1 = tm[lane * 4 + 1];
    float a2 = tm[lane * 4 + 2], a3 = tm[lane * 4 + 3];
    float g = -INFINITY;
#pragma unroll 1
    for (int j = 0; j < TOPK; ++j) {
      const float lm = fmaxf(fmaxf(a0, a1), fmaxf(a2, a3));
      g = lm;
#pragma unroll
      for (int off = 32; off > 0; off >>= 1) g = fmaxf(g, __shfl_xor(g, off, 64));
      const unsigned long long ball = __ballot(lm == g);
      const int src = __ffsll((long long)ball) - 1;
      if (lane == src) {
        if      (a0 == g) a0 = -INFINITY;
        else if (a1 == g) a1 = -INFINITY;
        else if (a2 == g) a2 = -INFINITY;
        else              a3 = -INFINITY;
      }
    }
    if (lane == 0) tts = g - TMARGIN;
  }
  __syncthreads();
  const float tt = tts;

  // --- chunk-skip scan: thread t handles 32-col group t ---
  if (tm[tid] >= tt) {
    const unsigned short* chunk = Sc + (size_t)r * NROWS + tid * 32;
#pragma unroll
    for (int k = 0; k < 4; ++k) {
      const uint4 u = *(const uint4*)&chunk[k * 8];
      const unsigned int uu[4] = {u.x, u.y, u.z, u.w};
#pragma unroll
      for (int e = 0; e < 4; ++e) {
        const float lo = __uint_as_float(uu[e] << 16);
        const float hi = __uint_as_float(uu[e] & 0xFFFF0000u);
        const int c0 = tid * 32 + k * 8 + 2 * e;
        if (lo >= tt) {
          const int p = atomicAdd(&lcnt, 1);
          if (p < CAP) lcand[p] = c0;
        }
        if (hi >= tt) {
          const int p = atomicAdd(&lcnt, 1);
          if (p < CAP) lcand[p] = c0 + 1;
        }
      }
    }
  }
  __syncthreads();   // candidate list complete
  if (wid != 0) return;

  // --- rescore on wave 0: chain BIT-IDENTICAL to rounds 3-20 ---
  const int n = min(lcnt, CAP);
  const bool active = lane < n;
  const int col = active ? lcand[lane] : 0;

  const float* a = Eh + (size_t)r * DIMK;
  const float* b = Et + (size_t)col * DIMK;
  float p = 0.f;
#pragma unroll 4
  for (int k = 0; k < DIMK; k += 4) {
    const float4 av = *(const float4*)&a[k];
    const float4 bv = *(const float4*)&b[k];
    p = fmaf(av.x, bv.x, p);
    p = fmaf(av.y, bv.y, p);
    p = fmaf(av.z, bv.z, p);
    p = fmaf(av.w, bv.w, p);
  }
  float v = active ? p * SCALE : -INFINITY;
  const int vc = active ? col : 0x7FFFFFFF;

  // 10 rounds of wave-max (tie -> min col); lane j keeps round-j winner.
  float myv = -INFINITY; int myc = 0; float m = 0.f;
  float vv = v; int cc2 = vc;
#pragma unroll 1
  for (int j = 0; j < TOPK; ++j) {
    float bvv = vv; int bcc = cc2;
#pragma unroll
    for (int off = 32; off > 0; off >>= 1) {
      const float ov = __shfl_xor(bvv, off, 64);
      const int oc = __shfl_xor(bcc, off, 64);
      if (ov > bvv || (ov == bvv && oc < bcc)) { bvv = ov; bcc = oc; }
    }
    if (j == 0) m = bvv;
    if (lane == j) { myv = bvv; myc = bcc; }
    if (vv == bvv && cc2 == bcc) vv = -INFINITY;   // knock out (cols unique)
  }

  // softmax: gather the 10 values, sum sequentially (rank order, as before).
  float sum = 0.f;
#pragma unroll
  for (int j = 0; j < TOPK; ++j) sum += expf(__shfl(myv, j, 64) - m);
  const float inv = 1.0f / sum;

  if (lane < TOPK) {
    const size_t ro = (size_t)r * TOPK + lane;
    out[ro] = (float)r;                                   // src
    out[(size_t)NROWS * TOPK + ro] = (float)myc;          // dst
    out[2 * (size_t)NROWS * TOPK + ro] = expf(myv - m) * inv;  // weight
  }
}

// ---------------------------------------------------------------------------
extern "C" void kernel_launch(void* const* d_in, const int* in_sizes, int n_in,
                              void* d_out, int out_size, void* d_ws, size_t ws_size,
                              hipStream_t stream) {
  const float* X  = (const float*)d_in[0];
  const float* Wh = (const float*)d_in[1];
  const float* bh = (const float*)d_in[2];
  const float* Wt = (const float*)d_in[3];
  const float* bt = (const float*)d_in[4];
  float* out = (float*)d_out;

  char* ws = (char*)d_ws;
  const size_t embB  = (size_t)NROWS * DIMK * sizeof(float);          // 16 MB
  const size_t embBH = (size_t)NROWS * DIMK * sizeof(unsigned short); //  8 MB
  const size_t tmaxB = (size_t)NROWS * NQ * sizeof(float);            //  8 MB
  float* Eh   = (float*)ws;
  float* Et   = (float*)(ws + embB);
  unsigned short* Ehb = (unsigned short*)(ws + 2 * embB);
  unsigned short* Etb = (unsigned short*)(ws + 2 * embB + embBH);
  float* tmax = (float*)(ws + 2 * embB + 2 * embBH);
  unsigned short* Sc = (unsigned short*)(ws + 2 * embB + 2 * embBH + tmaxB);
  // total ws use ~176 MB

  dim3 blk(NTHREADS);
  dim3 g1(NROWS / ETM, (2 * DIMK) / ETN);      // 64 x 8
  embed_gemm<<<g1, blk, 0, stream>>>(X, Wh, bh, Wt, bt, Eh, Et, Ehb, Etb);

  dim3 g2(NROWS / BM, NS2);                    // 64 x 16 (1024 blocks)
  screen_store<<<g2, blk, 0, stream>>>(Ehb, Etb, tmax, Sc);

  collect_rescore<<<NROWS, blk, 0, stream>>>(Sc, tmax, Eh, Et, out);
}